// Round 14
// baseline (187.308 us; speedup 1.0000x reference)
//
#include <hip/hip_runtime.h>
#include <math.h>

// Problem constants
#define BB    64
#define NEC   40000
#define NRC   500
#define D1C   200
#define D2C   200
#define LLC   64
#define BN_EPS 1e-5f
#define LOG2E 1.4426950408889634f

// ws layout (floats):
//   (xT/rT slots retained in layout but unused since R14 — stage1 is
//    self-contained)
//   taP   [L][64]         @ 25600  (2a, b-permuted: bp=(b&15)*4+(b>>4))
//   wP    [L][64]         @ 29696  (w*exp2(-a^2), b-permuted)
//   sl    [L]             @ 33792
//   x2Bh  bf16[64][256]   @ 33856  (bn1 out, b-major, K zero-padded, hi)
//   x2Bl  bf16[64][256]   @ 42048  (lo part)
//   y     [j][k][64]      @ 50240  (stage-1 partials, j-major)
#define WS_XT    0
#define WS_RT    12800
#define WS_TAP   25600
#define WS_WP    29696
#define WS_SL    33792
#define WS_X2BH  33856
#define WS_X2BL  42048
#define WS_Y     50240

typedef short s8v __attribute__((ext_vector_type(8)));   // 8 bf16 (4 VGPRs)
typedef float f4v __attribute__((ext_vector_type(4)));   // MFMA acc

__device__ __forceinline__ unsigned short bf16_rne(float x) {
  unsigned b = __float_as_uint(x);
  unsigned r = b + 0x7FFFu + ((b >> 16) & 1u);
  return (unsigned short)(r >> 16);
}
__device__ __forceinline__ void split2(float x, unsigned short& h,
                                       unsigned short& l) {
  h = bf16_rne(x);
  float hf = __uint_as_float(((unsigned)h) << 16);
  l = bf16_rne(x - hf);
}

typedef __attribute__((address_space(1))) const void gvoid_t;
typedef __attribute__((address_space(3))) void lvoid_t;
__device__ __forceinline__ void gload_lds16(const float* g, float* l) {
  __builtin_amdgcn_global_load_lds((gvoid_t*)g, (lvoid_t*)l, 16, 0, 0);
}

// ---------------------------------------------------------------------------
// Stage 1 v6: self-contained (prep kernel eliminated -> 3-kernel chain).
//   bn0 computed in-block: lane b loads E[e1_idx[b]*200+j] for wave-owned
//   j (= w+8t, wave-uniform -> scalar bn0g/bn0b loads), 64-lane shfl_xor
//   stats, normalized value written straight to xTl[j*64+lane]
//   (consecutive lanes -> conflict-free). W slab-0 prefetch issues FIRST so
//   bn0 compute hides under the gload_lds fills. rT -> 64-float LDS gather.
//   Redundant across 200 blocks but fully parallel; E's 64 rows are L2-hot.
//   LDS: 64K (Wb) + 51.2K (xTl) + 256B (rl) = 115.7 KB, 1 block/CU.
// ---------------------------------------------------------------------------
#define S1_STAGE(buf_, s_) do {                                         \
    int gbase_ = kbase + (s_) * 8000;                                   \
    _Pragma("unroll")                                                   \
    for (int r_ = 0; r_ < 4; r_++) {                                    \
      int off_ = r_ * 2048 + w * 256;                                   \
      int gi_ = gbase_ + off_ + lane4;                                  \
      gi_ = gi_ < 7999996 ? gi_ : 7999996;                              \
      gload_lds16(W + gi_, &Wb[buf_][off_]);                            \
    }                                                                   \
  } while (0)

__global__ __launch_bounds__(512) void stage1_kernel(
    const int* __restrict__ e1_idx, const int* __restrict__ r_idx,
    const float* __restrict__ E, const float* __restrict__ R,
    const float* __restrict__ bn0g, const float* __restrict__ bn0b,
    const float* __restrict__ W, float* __restrict__ y) {
  __shared__ float Wb[2][8192];      // 64 KB: 2 x (40 rows x 200 + pad)
  __shared__ float xTl[12800];       // 51.2 KB: bn0 output [j][64]
  __shared__ float rl[64];           // gathered relation row (this k)

  int k = blockIdx.x;
  int tid = threadIdx.x;
  int lane = tid & 63;
  int w = __builtin_amdgcn_readfirstlane(tid >> 6);
  int jc = w & 3, bh = w >> 2;
  int j4 = lane & 15, bq = lane >> 4;
  int j0 = jc * 64 + j4 * 4;         // 4 j's: j0..j0+3 (pad beyond 200)
  int b0 = bh * 32 + bq * 8;         // 8 b's
  bool jok = j0 < 200;               // waves 3,7: only j4<2 live
  int joff = jok ? j0 : 0;           // clamp LDS read addr for dead lanes
  int kbase = k * 40000;
  int lane4 = lane * 4;

  S1_STAGE(0, 0);                    // W slab 0 in flight under bn0 compute

  if (tid < 64) rl[tid] = R[r_idx[tid] * D2C + k];

  // bn0: wave w owns j = w, w+8, ..., w+192 (25 rows); lane = b.
  int eb = e1_idx[lane] * D1C;
#pragma unroll 5
  for (int t = 0; t < 25; t++) {
    int j = w + 8 * t;
    float e = E[eb + j];
    float sum = e, sq = e * e;
#pragma unroll
    for (int o = 32; o > 0; o >>= 1) {
      sum += __shfl_xor(sum, o, 64);
      sq  += __shfl_xor(sq,  o, 64);
    }
    float mean = sum * (1.f / 64.f);
    float var  = sq  * (1.f / 64.f) - mean * mean;
    float inv  = __builtin_amdgcn_rsqf(var + BN_EPS);
    float g    = bn0g[j] * inv;
    float be   = bn0b[j] - mean * g;
    xTl[j * 64 + lane] = g * e + be;
  }

  float acc[4][8];
#pragma unroll
  for (int jj = 0; jj < 4; jj++)
#pragma unroll
    for (int bb = 0; bb < 8; bb++) acc[jj][bb] = 0.f;

  for (int s = 0; s < 5; s++) {
    __syncthreads();                 // slab s ready; s=0 also fences bn0/rl
    if (s < 4) S1_STAGE((s + 1) & 1, s + 1);   // prefetch under compute
    const float* Ws = Wb[s & 1];
    const float* xrow = xTl + s * 40 * 64 + b0;
#pragma unroll 8
    for (int ri = 0; ri < 40; ri++) {
      float4 wv  = *(const float4*)(Ws + ri * 200 + joff);
      float4 xa  = *(const float4*)(xrow + ri * 64);
      float4 xb2 = *(const float4*)(xrow + ri * 64 + 4);
      float wc[4] = {wv.x, wv.y, wv.z, wv.w};
      float xv[8] = {xa.x, xa.y, xa.z, xa.w, xb2.x, xb2.y, xb2.z, xb2.w};
#pragma unroll
      for (int jj = 0; jj < 4; jj++)
#pragma unroll
        for (int bb = 0; bb < 8; bb++)
          acc[jj][bb] += wc[jj] * xv[bb];
    }
  }

  if (jok) {
    float4 r0 = *(const float4*)(rl + b0);
    float4 r1 = *(const float4*)(rl + b0 + 4);
    float rv[8] = {r0.x, r0.y, r0.z, r0.w, r1.x, r1.y, r1.z, r1.w};
#pragma unroll
    for (int jj = 0; jj < 4; jj++) {
      float* yo = y + ((j0 + jj) * 200 + k) * 64 + b0;   // j-major
      float4 o0 = make_float4(acc[jj][0] * rv[0], acc[jj][1] * rv[1],
                              acc[jj][2] * rv[2], acc[jj][3] * rv[3]);
      float4 o1 = make_float4(acc[jj][4] * rv[4], acc[jj][5] * rv[5],
                              acc[jj][6] * rv[6], acc[jj][7] * rv[7]);
      *(float4*)(yo) = o0;
      *(float4*)(yo + 4) = o1;
    }
  }
}

// ---------------------------------------------------------------------------
// Kernel C v4: reduce + bn1 (blocks 0-199, R13 streaming version) AND the
// absorbed prep work (blocks 200-208):
//   200-207: taP/wP transform, 8-way split (+ sl on block 200)
//   208    : zero ONLY the K-pad cols 200..255 of x2Bh/x2Bl (word-disjoint
//            from the bn1 writes of blocks 0-199 -> no intra-kernel race)
// ---------------------------------------------------------------------------
__global__ __launch_bounds__(256) void reduce_bn1_kernel(
    const float* __restrict__ y, const float* __restrict__ lits,
    const float* __restrict__ c, const float* __restrict__ var_l,
    const float* __restrict__ nf, const int* __restrict__ e1_idx,
    const int* __restrict__ r_idx, const float* __restrict__ bn1g,
    const float* __restrict__ bn1b, float* __restrict__ ws) {
  int bid = blockIdx.x;
  int tid = threadIdx.x;

  if (bid < 200) {
    int j = bid;
    int b = tid & 63, kq = tid >> 6;
    float s = 0.f;
    const float* yp = y + (j * 200 + kq * 50) * 64 + b;
#pragma unroll 10
    for (int k = 0; k < 50; k++) s += yp[k * 64];

    __shared__ float part[256];
    part[tid] = s;
    __syncthreads();
    if (tid < 64) {
      float v = part[tid] + part[64 + tid] + part[128 + tid] + part[192 + tid];
      float sum = v, sq = v * v;
#pragma unroll
      for (int o = 32; o > 0; o >>= 1) {
        sum += __shfl_xor(sum, o, 64);
        sq  += __shfl_xor(sq,  o, 64);
      }
      float mean = sum * (1.f / 64.f);
      float var  = sq  * (1.f / 64.f) - mean * mean;
      float inv  = __builtin_amdgcn_rsqf(var + BN_EPS);
      float g    = bn1g[j] * inv;
      float be   = bn1b[j] - mean * g;
      float xv   = g * v + be;
      unsigned short h, l;
      split2(xv, h, l);
      unsigned short* xh = (unsigned short*)(ws + WS_X2BH);
      unsigned short* xl = (unsigned short*)(ws + WS_X2BL);
      xh[tid * 256 + j] = h;
      xl[tid * 256 + j] = l;
    }
  } else if (bid <= 207) {
    // w*exp2(-(a-L)^2) = [w*exp2(-a^2)] * exp2(fma(2a, L, -L^2))
    // stored with b-permutation bp = (b&15)*4 + (b>>4) to match MFMA C-layout
    float* taP = ws + WS_TAP;
    float* wP  = ws + WS_WP;
    float* sl  = ws + WS_SL;
    int part = bid - 200;                    // 0..7, 512 elems each
#pragma unroll
    for (int it = 0; it < 2; it++) {
      int idx = part * 512 + it * 256 + tid;
      int b = idx >> 6, l = idx & 63;
      float s = sqrtf(LOG2E / var_l[l]);
      float a = (lits[e1_idx[b] * LLC + l] - c[l]) * s;
      int bp = (b & 15) * 4 + (b >> 4);
      taP[l * 64 + bp] = a + a;
      wP[l * 64 + bp]  = nf[r_idx[b] * LLC + l] * __builtin_amdgcn_exp2f(-a * a);
    }
    if (bid == 200 && tid < LLC) sl[tid] = sqrtf(LOG2E / var_l[tid]);
  } else {
    // zero the K-pad: cols 200..255 of each 256-col b-row = words
    // [b*128+100, b*128+127] per array; 64 rows x 28 words x 2 arrays.
    unsigned* z = (unsigned*)(ws + WS_X2BH);   // x2bl starts at word 8192
    for (int idx = tid; idx < 64 * 28 * 2; idx += 256) {
      int a  = idx >= 1792 ? 1 : 0;            // 64*28 = 1792
      int i2 = idx - a * 1792;
      int r  = i2 / 28, cw = i2 % 28;
      z[a * 8192 + r * 128 + 100 + cw] = 0u;
    }
  }
}

// ---------------------------------------------------------------------------
// Final (R6 version, measured-best ~47.5 us; pinned after 5 failed
// restructures R2/R3/R4/R5/R7 — occupancy is NOT its limiter): score_l via
// split-bf16 MFMA 16x16x32; score_n via R8 loop on the C-fragment mapping.
// grid 625, 256 thr = 4 waves.
// ---------------------------------------------------------------------------
__global__ __launch_bounds__(256, 4) void final_kernel(
    const float* __restrict__ E, const float* __restrict__ lits,
    const float* __restrict__ ws, float* __restrict__ out) {
  const float* taP = ws + WS_TAP;
  const float* wP  = ws + WS_WP;
  const float* sl  = ws + WS_SL;
  const unsigned short* x2bh = (const unsigned short*)(ws + WS_X2BH);
  const unsigned short* x2bl = (const unsigned short*)(ws + WS_X2BL);

  __shared__ float SM[9216];                 // 36864 B arena
  unsigned short* Ah = (unsigned short*)SM;  // [64][72] bf16
  unsigned short* Al = Ah + 4608;
  unsigned short* Bh = Ah + 9216;
  unsigned short* Bl = Ah + 13824;

  int n0 = blockIdx.x * 64;
  int tid = threadIdx.x;
  int lane = tid & 63;
  int w = __builtin_amdgcn_readfirstlane(tid >> 6);
  int ln = lane & 15;
  int quad = lane >> 4;

  f4v acc[4];
#pragma unroll
  for (int t = 0; t < 4; t++) acc[t] = (f4v){0.f, 0.f, 0.f, 0.f};

  // ---- score_l: 4 K-slabs of 64 ----
  for (int q = 0; q < 4; q++) {
    int k0 = q * 64;
    __syncthreads();
    // stage E slab -> Ah/Al (split-bf16 on the fly)
#pragma unroll
    for (int it = 0; it < 4; it++) {
      int idx = tid + it * 256;
      int row = idx >> 4, c4 = idx & 15, cc = c4 * 4;
      float4 v = make_float4(0.f, 0.f, 0.f, 0.f);
      if (k0 + cc < 200) v = *(const float4*)(E + (n0 + row) * D1C + k0 + cc);
      unsigned short h0, l0, h1, l1, h2, l2, h3, l3;
      split2(v.x, h0, l0); split2(v.y, h1, l1);
      split2(v.z, h2, l2); split2(v.w, h3, l3);
      *(ushort4*)(Ah + row * 72 + cc) = make_ushort4(h0, h1, h2, h3);
      *(ushort4*)(Al + row * 72 + cc) = make_ushort4(l0, l1, l2, l3);
    }
    // stage x2B slab -> Bh/Bl (straight copy; K-pad already zeroed)
#pragma unroll
    for (int it = 0; it < 4; it++) {
      int idx = tid + it * 256;
      int row = idx >> 4, c4 = idx & 15;
      *(ushort4*)(Bh + row * 72 + c4 * 4) =
          *(const ushort4*)(x2bh + row * 256 + k0 + c4 * 4);
      *(ushort4*)(Bl + row * 72 + c4 * 4) =
          *(const ushort4*)(x2bl + row * 256 + k0 + c4 * 4);
    }
    __syncthreads();

    const unsigned short* Ab  = Ah + (16 * w + ln) * 72 + quad * 8;
    const unsigned short* Alb = Al + (16 * w + ln) * 72 + quad * 8;
#pragma unroll
    for (int ks = 0; ks < 64; ks += 32) {
      s8v ah = *(const s8v*)(Ab + ks);
      s8v al = *(const s8v*)(Alb + ks);
#pragma unroll
      for (int t = 0; t < 4; t++) {
        s8v bh = *(const s8v*)(Bh + (16 * t + ln) * 72 + quad * 8 + ks);
        s8v bl = *(const s8v*)(Bl + (16 * t + ln) * 72 + quad * 8 + ks);
        acc[t] = __builtin_amdgcn_mfma_f32_16x16x32_bf16(ah, bh, acc[t], 0, 0, 0);
        acc[t] = __builtin_amdgcn_mfma_f32_16x16x32_bf16(al, bh, acc[t], 0, 0, 0);
        acc[t] = __builtin_amdgcn_mfma_f32_16x16x32_bf16(ah, bl, acc[t], 0, 0, 0);
      }
    }
  }

  // ---- phase B: score_n on the C-fragment mapping ----
  float* Llds = SM;           // [64][68] scaled lits, rows=l, cols=n-local
  float* TAl  = SM + 4352;    // [32][64] ta half (b-permuted)
  float* Wl   = SM + 6400;    // [32][64]
  int nlb = 16 * w + 4 * quad;

  __syncthreads();
#pragma unroll
  for (int it = 0; it < 4; it++) {
    int idx = tid + it * 256;
    int row = idx >> 4, c4 = idx & 15;
    float4 v = *(const float4*)(lits + (n0 + row) * LLC + c4 * 4);
    int l = c4 * 4;
    Llds[(l + 0) * 68 + row] = v.x * sl[l + 0];
    Llds[(l + 1) * 68 + row] = v.y * sl[l + 1];
    Llds[(l + 2) * 68 + row] = v.z * sl[l + 2];
    Llds[(l + 3) * 68 + row] = v.w * sl[l + 3];
  }

  for (int h = 0; h < 2; h++) {
    __syncthreads();          // h=0: Llds staged; h=1: previous reads done
#pragma unroll
    for (int it = 0; it < 2; it++) {
      int idx = tid + it * 256;
      ((float4*)TAl)[idx] = ((const float4*)(taP + h * 2048))[idx];
      ((float4*)Wl)[idx]  = ((const float4*)(wP  + h * 2048))[idx];
    }
    __syncthreads();
    for (int ll = 0; ll < 32; ll++) {
      float4 Lv = *(const float4*)(Llds + (h * 32 + ll) * 68 + nlb);
      float4 ta = *(const float4*)(TAl + ll * 64 + 4 * ln);
      float4 wv = *(const float4*)(Wl  + ll * 64 + 4 * ln);
      float Lc[4]  = {Lv.x, Lv.y, Lv.z, Lv.w};
      float tac[4] = {ta.x, ta.y, ta.z, ta.w};
      float wvc[4] = {wv.x, wv.y, wv.z, wv.w};
      float n2[4];
#pragma unroll
      for (int r = 0; r < 4; r++) n2[r] = -Lc[r] * Lc[r];
#pragma unroll
      for (int t = 0; t < 4; t++) {
#pragma unroll
        for (int r = 0; r < 4; r++) {
          acc[t][r] += wvc[t] *
              __builtin_amdgcn_exp2f(__builtin_fmaf(tac[t], Lc[r], n2[r]));
        }
      }
    }
  }

  // ---- sigmoid + float4 stores (4 consecutive n per b-row) ----
#pragma unroll
  for (int t = 0; t < 4; t++) {
    float4 o;
    o.x = __builtin_amdgcn_rcpf(1.f + __builtin_amdgcn_exp2f(-LOG2E * acc[t][0]));
    o.y = __builtin_amdgcn_rcpf(1.f + __builtin_amdgcn_exp2f(-LOG2E * acc[t][1]));
    o.z = __builtin_amdgcn_rcpf(1.f + __builtin_amdgcn_exp2f(-LOG2E * acc[t][2]));
    o.w = __builtin_amdgcn_rcpf(1.f + __builtin_amdgcn_exp2f(-LOG2E * acc[t][3]));
    *(float4*)(out + (size_t)(16 * t + ln) * NEC + n0 + nlb) = o;
  }
}

// ---------------------------------------------------------------------------
extern "C" void kernel_launch(void* const* d_in, const int* in_sizes, int n_in,
                              void* d_out, int out_size, void* d_ws, size_t ws_size,
                              hipStream_t stream) {
  (void)in_sizes; (void)n_in; (void)out_size; (void)ws_size;
  const int*   e1    = (const int*)d_in[0];
  const int*   ri    = (const int*)d_in[1];
  const float* E     = (const float*)d_in[2];
  const float* R     = (const float*)d_in[3];
  const float* W     = (const float*)d_in[4];
  const float* lits  = (const float*)d_in[5];
  const float* c     = (const float*)d_in[6];
  const float* var_l = (const float*)d_in[7];
  const float* nf    = (const float*)d_in[8];
  const float* bn0g  = (const float*)d_in[9];
  const float* bn0b  = (const float*)d_in[10];
  const float* bn1g  = (const float*)d_in[11];
  const float* bn1b  = (const float*)d_in[12];
  float* out = (float*)d_out;
  float* ws  = (float*)d_ws;
  float* y   = ws + WS_Y;

  stage1_kernel<<<200, 512, 0, stream>>>(e1, ri, E, R, bn0g, bn0b, W, y);
  reduce_bn1_kernel<<<209, 256, 0, stream>>>(y, lits, c, var_l, nf,
                                             e1, ri, bn1g, bn1b, ws);
  final_kernel<<<625, 256, 0, stream>>>(E, lits, ws, out);
}

// Round 15
// 186.756 us; speedup vs baseline: 1.0030x; 1.0030x over previous
//
#include <hip/hip_runtime.h>
#include <math.h>

// Problem constants
#define BB    64
#define NEC   40000
#define NRC   500
#define D1C   200
#define D2C   200
#define LLC   64
#define BN_EPS 1e-5f
#define LOG2E 1.4426950408889634f

// ws layout (floats):
//   xT    [D1][64]        @ 0      (bn0 output, transposed)
//   rT    [D2][64]        @ 12800  (gathered relation rows)
//   taP   [L][64]         @ 25600  (2a, b-permuted: bp=(b&15)*4+(b>>4))
//   wP    [L][64]         @ 29696  (w*exp2(-a^2), b-permuted)
//   sl    [L]             @ 33792
//   x2Bh  bf16[64][256]   @ 33856  (bn1 out, b-major, K zero-padded, hi)
//   x2Bl  bf16[64][256]   @ 42048  (lo part)
//   y     [j][k][64]      @ 50240  (stage-1 partials, j-major)
#define WS_XT    0
#define WS_RT    12800
#define WS_TAP   25600
#define WS_WP    29696
#define WS_SL    33792
#define WS_X2BH  33856
#define WS_X2BL  42048
#define WS_Y     50240

typedef short s8v __attribute__((ext_vector_type(8)));   // 8 bf16 (4 VGPRs)
typedef float f4v __attribute__((ext_vector_type(4)));   // MFMA acc

__device__ __forceinline__ unsigned short bf16_rne(float x) {
  unsigned b = __float_as_uint(x);
  unsigned r = b + 0x7FFFu + ((b >> 16) & 1u);
  return (unsigned short)(r >> 16);
}
__device__ __forceinline__ void split2(float x, unsigned short& h,
                                       unsigned short& l) {
  h = bf16_rne(x);
  float hf = __uint_as_float(((unsigned)h) << 16);
  l = bf16_rne(x - hf);
}

typedef __attribute__((address_space(1))) const void gvoid_t;
typedef __attribute__((address_space(3))) void lvoid_t;
__device__ __forceinline__ void gload_lds16(const float* g, float* l) {
  __builtin_amdgcn_global_load_lds((gvoid_t*)g, (lvoid_t*)l, 16, 0, 0);
}

// ---------------------------------------------------------------------------
// Kernel A v4 (R12/R13, measured win): prep spread over 16 blocks.
//   block 0      : bn0 (register-cached gather)
//   blocks 1-4   : rT gather, 4-way split
//   blocks 5-12  : taP/wP transform, 8-way split (+ sl on block 5)
//   blocks 13-15 : x2B zero, 3-way strided
// ---------------------------------------------------------------------------
__global__ __launch_bounds__(256) void prep_kernel(
    const int* __restrict__ e1_idx, const int* __restrict__ r_idx,
    const float* __restrict__ E, const float* __restrict__ R,
    const float* __restrict__ lits, const float* __restrict__ c,
    const float* __restrict__ var_l, const float* __restrict__ nf,
    const float* __restrict__ bn0g, const float* __restrict__ bn0b,
    float* __restrict__ ws) {
  float* xT  = ws + WS_XT;
  float* rT  = ws + WS_RT;
  float* taP = ws + WS_TAP;
  float* wP  = ws + WS_WP;
  float* sl  = ws + WS_SL;
  int tid = threadIdx.x;
  int bid = blockIdx.x;

  if (bid == 0) {
    if (tid < D1C) {
      int j = tid;
      float ev[64];
      float sum = 0.f, sq = 0.f;
#pragma unroll
      for (int b = 0; b < BB; b++) {
        float e = E[e1_idx[b] * D1C + j];
        ev[b] = e;
        sum += e; sq += e * e;
      }
      float mean = sum * (1.f / 64.f);
      float var  = sq  * (1.f / 64.f) - mean * mean;
      float inv  = __builtin_amdgcn_rsqf(var + BN_EPS);
      float g    = bn0g[j] * inv;
      float be   = bn0b[j] - mean * g;
#pragma unroll
      for (int b = 0; b < BB; b++) {
        xT[j * 64 + b] = g * ev[b] + be;
      }
    }
  } else if (bid <= 4) {
    int part = bid - 1;                      // 0..3, 3200 elems each
    int end = part * 3200 + 3200;
    for (int idx = part * 3200 + tid; idx < end; idx += 256) {
      int k = idx >> 6, b = idx & 63;
      rT[idx] = R[r_idx[b] * D2C + k];
    }
  } else if (bid <= 12) {
    // w*exp2(-(a-L)^2) = [w*exp2(-a^2)] * exp2(fma(2a, L, -L^2))
    // stored with b-permutation bp = (b&15)*4 + (b>>4) to match MFMA C-layout
    int part = bid - 5;                      // 0..7, 512 elems each
#pragma unroll
    for (int it = 0; it < 2; it++) {
      int idx = part * 512 + it * 256 + tid;
      int b = idx >> 6, l = idx & 63;
      float s = sqrtf(LOG2E / var_l[l]);
      float a = (lits[e1_idx[b] * LLC + l] - c[l]) * s;
      int bp = (b & 15) * 4 + (b >> 4);
      taP[l * 64 + bp] = a + a;
      wP[l * 64 + bp]  = nf[r_idx[b] * LLC + l] * __builtin_amdgcn_exp2f(-a * a);
    }
    if (bid == 5 && tid < LLC) sl[tid] = sqrtf(LOG2E / var_l[tid]);
  } else {
    // zero x2Bh/x2Bl (covers K padding 200..255), 3 blocks strided
    unsigned* z = (unsigned*)(ws + WS_X2BH);
    for (int i = (bid - 13) * 256 + tid; i < 16384; i += 768) z[i] = 0u;
  }
}

// ---------------------------------------------------------------------------
// Stage 1 v3 (R13, proven best of 6 designs): lane-parallel W via
// double-buffered LDS slabs + xT in LDS; y written j-major for streaming
// reduce. global_load_lds = fire-and-forget (no VGPR dependency chain);
// ds_reads dual-issue under the 32-FMA bursts.
// ---------------------------------------------------------------------------
#define S1_STAGE(buf_, s_) do {                                         \
    int gbase_ = kbase + (s_) * 8000;                                   \
    _Pragma("unroll")                                                   \
    for (int r_ = 0; r_ < 4; r_++) {                                    \
      int off_ = r_ * 2048 + w * 256;                                   \
      int gi_ = gbase_ + off_ + lane4;                                  \
      gi_ = gi_ < 7999996 ? gi_ : 7999996;                              \
      gload_lds16(W + gi_, &Wb[buf_][off_]);                            \
    }                                                                   \
  } while (0)

__global__ __launch_bounds__(512) void stage1_kernel(
    const float* __restrict__ W, const float* __restrict__ ws_in,
    float* __restrict__ y) {
  const float* xTg = ws_in + WS_XT;  // [i][64] (global)
  const float* rT  = ws_in + WS_RT;  // [k][64]
  __shared__ float Wb[2][8192];      // 64 KB: 2 x (40 rows x 200 + pad)
  __shared__ float xTl[12800];       // 51.2 KB: full xT

  int k = blockIdx.x;
  int tid = threadIdx.x;
  int lane = tid & 63;
  int w = __builtin_amdgcn_readfirstlane(tid >> 6);
  int jc = w & 3, bh = w >> 2;
  int j4 = lane & 15, bq = lane >> 4;
  int j0 = jc * 64 + j4 * 4;         // 4 j's: j0..j0+3 (pad beyond 200)
  int b0 = bh * 32 + bq * 8;         // 8 b's
  bool jok = j0 < 200;               // waves 3,7: only j4<2 live
  int joff = jok ? j0 : 0;           // clamp LDS read addr for dead lanes
  int kbase = k * 40000;
  int lane4 = lane * 4;

  // stage full xT -> LDS: 12800 floats = 50 wave-chunks of 256 floats
  for (int cc = w; cc < 50; cc += 8) {
    gload_lds16(xTg + cc * 256 + lane4, &xTl[cc * 256]);
  }
  S1_STAGE(0, 0);

  float acc[4][8];
#pragma unroll
  for (int jj = 0; jj < 4; jj++)
#pragma unroll
    for (int bb = 0; bb < 8; bb++) acc[jj][bb] = 0.f;

  for (int s = 0; s < 5; s++) {
    __syncthreads();                 // drains vmcnt -> slab s (and xT) ready
    if (s < 4) S1_STAGE((s + 1) & 1, s + 1);   // prefetch under compute
    const float* Ws = Wb[s & 1];
    const float* xrow = xTl + s * 40 * 64 + b0;
#pragma unroll 8
    for (int ri = 0; ri < 40; ri++) {
      float4 wv  = *(const float4*)(Ws + ri * 200 + joff);
      float4 xa  = *(const float4*)(xrow + ri * 64);
      float4 xb2 = *(const float4*)(xrow + ri * 64 + 4);
      float wc[4] = {wv.x, wv.y, wv.z, wv.w};
      float xv[8] = {xa.x, xa.y, xa.z, xa.w, xb2.x, xb2.y, xb2.z, xb2.w};
#pragma unroll
      for (int jj = 0; jj < 4; jj++)
#pragma unroll
        for (int bb = 0; bb < 8; bb++)
          acc[jj][bb] += wc[jj] * xv[bb];
    }
  }

  if (jok) {
    float4 r0 = *(const float4*)(rT + k * 64 + b0);
    float4 r1 = *(const float4*)(rT + k * 64 + b0 + 4);
    float rv[8] = {r0.x, r0.y, r0.z, r0.w, r1.x, r1.y, r1.z, r1.w};
#pragma unroll
    for (int jj = 0; jj < 4; jj++) {
      float* yo = y + ((j0 + jj) * 200 + k) * 64 + b0;   // j-major
      float4 o0 = make_float4(acc[jj][0] * rv[0], acc[jj][1] * rv[1],
                              acc[jj][2] * rv[2], acc[jj][3] * rv[3]);
      float4 o1 = make_float4(acc[jj][4] * rv[4], acc[jj][5] * rv[5],
                              acc[jj][6] * rv[6], acc[jj][7] * rv[7]);
      *(float4*)(yo) = o0;
      *(float4*)(yo + 4) = o1;
    }
  }
}

// ---------------------------------------------------------------------------
// Kernel C v3 (R13): STREAMING reduce over j-major y. Block j owns one
// contiguous 51.2 KB span; thread (kq,b) sums 50 k at 256-B stride.
// ---------------------------------------------------------------------------
__global__ __launch_bounds__(256) void reduce_bn1_kernel(
    const float* __restrict__ y, const float* __restrict__ bn1g,
    const float* __restrict__ bn1b, float* __restrict__ ws) {
  int j = blockIdx.x;
  int tid = threadIdx.x, b = tid & 63, kq = tid >> 6;

  float s = 0.f;
  const float* yp = y + (j * 200 + kq * 50) * 64 + b;
#pragma unroll 10
  for (int k = 0; k < 50; k++) s += yp[k * 64];

  __shared__ float part[256];
  part[tid] = s;
  __syncthreads();
  if (tid < 64) {
    float v = part[tid] + part[64 + tid] + part[128 + tid] + part[192 + tid];
    float sum = v, sq = v * v;
#pragma unroll
    for (int o = 32; o > 0; o >>= 1) {
      sum += __shfl_xor(sum, o, 64);
      sq  += __shfl_xor(sq,  o, 64);
    }
    float mean = sum * (1.f / 64.f);
    float var  = sq  * (1.f / 64.f) - mean * mean;
    float inv  = __builtin_amdgcn_rsqf(var + BN_EPS);
    float g    = bn1g[j] * inv;
    float be   = bn1b[j] - mean * g;
    float xv   = g * v + be;
    unsigned short h, l;
    split2(xv, h, l);
    unsigned short* xh = (unsigned short*)(ws + WS_X2BH);
    unsigned short* xl = (unsigned short*)(ws + WS_X2BL);
    xh[tid * 256 + j] = h;
    xl[tid * 256 + j] = l;
  }
}

// ---------------------------------------------------------------------------
// Final v5: R13's pinned phase A unchanged; phase B restructured from
// 5 barriers to 2. Old: {bar, stage Llds} + 2x {bar, stage 16KB TA/WV half,
// bar, 32 ll}. New: stage Llds + FULL TA[64][64] + WV[64][64] in one pass,
// ONE barrier, then 64 uninterrupted ll iterations. Arena 36.9 -> 50.7 KB
// (still 3 blocks/CU >= grid's 2.44). Same compute addressing, same
// conflict profile; removes 3 barrier-lockstep stalls + one exposed
// mid-phase staging latency per block.
// ---------------------------------------------------------------------------
__global__ __launch_bounds__(256, 3) void final_kernel(
    const float* __restrict__ E, const float* __restrict__ lits,
    const float* __restrict__ ws, float* __restrict__ out) {
  const float* taP = ws + WS_TAP;
  const float* wP  = ws + WS_WP;
  const float* sl  = ws + WS_SL;
  const unsigned short* x2bh = (const unsigned short*)(ws + WS_X2BH);
  const unsigned short* x2bl = (const unsigned short*)(ws + WS_X2BL);

  __shared__ float SM[12544];                // 50176 B arena
  unsigned short* Ah = (unsigned short*)SM;  // [64][72] bf16
  unsigned short* Al = Ah + 4608;
  unsigned short* Bh = Ah + 9216;
  unsigned short* Bl = Ah + 13824;

  int n0 = blockIdx.x * 64;
  int tid = threadIdx.x;
  int lane = tid & 63;
  int w = __builtin_amdgcn_readfirstlane(tid >> 6);
  int ln = lane & 15;
  int quad = lane >> 4;

  f4v acc[4];
#pragma unroll
  for (int t = 0; t < 4; t++) acc[t] = (f4v){0.f, 0.f, 0.f, 0.f};

  // ---- score_l: 4 K-slabs of 64 ----
  for (int q = 0; q < 4; q++) {
    int k0 = q * 64;
    __syncthreads();
    // stage E slab -> Ah/Al (split-bf16 on the fly)
#pragma unroll
    for (int it = 0; it < 4; it++) {
      int idx = tid + it * 256;
      int row = idx >> 4, c4 = idx & 15, cc = c4 * 4;
      float4 v = make_float4(0.f, 0.f, 0.f, 0.f);
      if (k0 + cc < 200) v = *(const float4*)(E + (n0 + row) * D1C + k0 + cc);
      unsigned short h0, l0, h1, l1, h2, l2, h3, l3;
      split2(v.x, h0, l0); split2(v.y, h1, l1);
      split2(v.z, h2, l2); split2(v.w, h3, l3);
      *(ushort4*)(Ah + row * 72 + cc) = make_ushort4(h0, h1, h2, h3);
      *(ushort4*)(Al + row * 72 + cc) = make_ushort4(l0, l1, l2, l3);
    }
    // stage x2B slab -> Bh/Bl (straight copy; K-pad already zeroed)
#pragma unroll
    for (int it = 0; it < 4; it++) {
      int idx = tid + it * 256;
      int row = idx >> 4, c4 = idx & 15;
      *(ushort4*)(Bh + row * 72 + c4 * 4) =
          *(const ushort4*)(x2bh + row * 256 + k0 + c4 * 4);
      *(ushort4*)(Bl + row * 72 + c4 * 4) =
          *(const ushort4*)(x2bl + row * 256 + k0 + c4 * 4);
    }
    __syncthreads();

    const unsigned short* Ab  = Ah + (16 * w + ln) * 72 + quad * 8;
    const unsigned short* Alb = Al + (16 * w + ln) * 72 + quad * 8;
#pragma unroll
    for (int ks = 0; ks < 64; ks += 32) {
      s8v ah = *(const s8v*)(Ab + ks);
      s8v al = *(const s8v*)(Alb + ks);
#pragma unroll
      for (int t = 0; t < 4; t++) {
        s8v bh = *(const s8v*)(Bh + (16 * t + ln) * 72 + quad * 8 + ks);
        s8v bl = *(const s8v*)(Bl + (16 * t + ln) * 72 + quad * 8 + ks);
        acc[t] = __builtin_amdgcn_mfma_f32_16x16x32_bf16(ah, bh, acc[t], 0, 0, 0);
        acc[t] = __builtin_amdgcn_mfma_f32_16x16x32_bf16(al, bh, acc[t], 0, 0, 0);
        acc[t] = __builtin_amdgcn_mfma_f32_16x16x32_bf16(ah, bl, acc[t], 0, 0, 0);
      }
    }
  }

  // ---- phase B: score_n, single-barrier form ----
  float* Llds = SM;           // [64][68] scaled lits, rows=l, cols=n-local
  float* TA   = SM + 4352;    // [64][64] full 2a (b-permuted)
  float* WV   = SM + 8448;    // [64][64] full w (b-permuted)
  int nlb = 16 * w + 4 * quad;

  __syncthreads();            // phase A frag reads done
#pragma unroll
  for (int it = 0; it < 4; it++) {
    int idx = tid + it * 256;
    int row = idx >> 4, c4 = idx & 15;
    float4 v = *(const float4*)(lits + (n0 + row) * LLC + c4 * 4);
    int l = c4 * 4;
    Llds[(l + 0) * 68 + row] = v.x * sl[l + 0];
    Llds[(l + 1) * 68 + row] = v.y * sl[l + 1];
    Llds[(l + 2) * 68 + row] = v.z * sl[l + 2];
    Llds[(l + 3) * 68 + row] = v.w * sl[l + 3];
    ((float4*)TA)[idx] = ((const float4*)taP)[idx];
    ((float4*)WV)[idx] = ((const float4*)wP)[idx];
  }
  __syncthreads();            // everything staged; no more barriers

  for (int ll = 0; ll < 64; ll++) {
    float4 Lv = *(const float4*)(Llds + ll * 68 + nlb);
    float4 ta = *(const float4*)(TA + ll * 64 + 4 * ln);
    float4 wv = *(const float4*)(WV + ll * 64 + 4 * ln);
    float Lc[4]  = {Lv.x, Lv.y, Lv.z, Lv.w};
    float tac[4] = {ta.x, ta.y, ta.z, ta.w};
    float wvc[4] = {wv.x, wv.y, wv.z, wv.w};
    float n2[4];
#pragma unroll
    for (int r = 0; r < 4; r++) n2[r] = -Lc[r] * Lc[r];
#pragma unroll
    for (int t = 0; t < 4; t++) {
#pragma unroll
      for (int r = 0; r < 4; r++) {
        acc[t][r] += wvc[t] *
            __builtin_amdgcn_exp2f(__builtin_fmaf(tac[t], Lc[r], n2[r]));
      }
    }
  }

  // ---- sigmoid + float4 stores (4 consecutive n per b-row) ----
#pragma unroll
  for (int t = 0; t < 4; t++) {
    float4 o;
    o.x = __builtin_amdgcn_rcpf(1.f + __builtin_amdgcn_exp2f(-LOG2E * acc[t][0]));
    o.y = __builtin_amdgcn_rcpf(1.f + __builtin_amdgcn_exp2f(-LOG2E * acc[t][1]));
    o.z = __builtin_amdgcn_rcpf(1.f + __builtin_amdgcn_exp2f(-LOG2E * acc[t][2]));
    o.w = __builtin_amdgcn_rcpf(1.f + __builtin_amdgcn_exp2f(-LOG2E * acc[t][3]));
    *(float4*)(out + (size_t)(16 * t + ln) * NEC + n0 + nlb) = o;
  }
}

// ---------------------------------------------------------------------------
extern "C" void kernel_launch(void* const* d_in, const int* in_sizes, int n_in,
                              void* d_out, int out_size, void* d_ws, size_t ws_size,
                              hipStream_t stream) {
  (void)in_sizes; (void)n_in; (void)out_size; (void)ws_size;
  const int*   e1    = (const int*)d_in[0];
  const int*   ri    = (const int*)d_in[1];
  const float* E     = (const float*)d_in[2];
  const float* R     = (const float*)d_in[3];
  const float* W     = (const float*)d_in[4];
  const float* lits  = (const float*)d_in[5];
  const float* c     = (const float*)d_in[6];
  const float* var_l = (const float*)d_in[7];
  const float* nf    = (const float*)d_in[8];
  const float* bn0g  = (const float*)d_in[9];
  const float* bn0b  = (const float*)d_in[10];
  const float* bn1g  = (const float*)d_in[11];
  const float* bn1b  = (const float*)d_in[12];
  float* out = (float*)d_out;
  float* ws  = (float*)d_ws;
  float* y   = ws + WS_Y;

  prep_kernel<<<16, 256, 0, stream>>>(e1, ri, E, R, lits, c, var_l, nf,
                                      bn0g, bn0b, ws);
  stage1_kernel<<<200, 512, 0, stream>>>(W, ws, y);
  reduce_bn1_kernel<<<200, 256, 0, stream>>>(y, bn1g, bn1b, ws);
  final_kernel<<<625, 256, 0, stream>>>(E, lits, ws, out);
}